// Round 1
// baseline (68.437 us; speedup 1.0000x reference)
//
#include <hip/hip_runtime.h>

#define D_ 32
#define H_ 128
#define B_ 32
#define NSTEPS 48

// Dormand-Prince coefficients (computed in double, rounded to f32 like JAX weak typing)
__constant__ float cA[6][6] = {
  {(float)(0.2), 0.f, 0.f, 0.f, 0.f, 0.f},
  {(float)(3.0/40.0), (float)(9.0/40.0), 0.f, 0.f, 0.f, 0.f},
  {(float)(44.0/45.0), (float)(-56.0/15.0), (float)(32.0/9.0), 0.f, 0.f, 0.f},
  {(float)(19372.0/6561.0), (float)(-25360.0/2187.0), (float)(64448.0/6561.0), (float)(-212.0/729.0), 0.f, 0.f},
  {(float)(9017.0/3168.0), (float)(-355.0/33.0), (float)(46732.0/5247.0), (float)(49.0/176.0), (float)(-5103.0/18656.0), 0.f},
  {(float)(35.0/384.0), 0.f, (float)(500.0/1113.0), (float)(125.0/192.0), (float)(-2187.0/6784.0), (float)(11.0/84.0)}
};
__constant__ float cC[6] = {0.2f, 0.3f, 0.8f, (float)(8.0/9.0), 1.0f, 1.0f};
__constant__ float cB5[6] = {(float)(35.0/384.0), 0.f, (float)(500.0/1113.0), (float)(125.0/192.0),
                             (float)(-2187.0/6784.0), (float)(11.0/84.0)};
__constant__ float cE[7] = {
  (float)(35.0/384.0 - 5179.0/57600.0), 0.f,
  (float)(500.0/1113.0 - 7571.0/16695.0),
  (float)(125.0/192.0 - 393.0/640.0),
  (float)(-2187.0/6784.0 + 92097.0/339200.0),
  (float)(11.0/84.0 - 187.0/2100.0),
  (float)(-1.0/40.0)
};

// G[k][i] = W2[k][i] * M[i][k],  M[i][k] = sum_d W1[i][d] * W3[d][k]  (d < D)
// trace(J) = d2^T (G d1)
__global__ void g_precompute(const float* __restrict__ W1, const float* __restrict__ W2,
                             const float* __restrict__ W3, float* __restrict__ G) {
  int k = blockIdx.x;   // layer-2 hidden index
  int i = threadIdx.x;  // layer-1 hidden index
  float m = 0.f;
  #pragma unroll
  for (int d = 0; d < D_; ++d) m += W1[i*(D_+1) + d] * W3[d*H_ + k];
  G[k*H_ + i] = W2[k*H_ + i] * m;
}

__global__ __launch_bounds__(512)
void node_solve(const float* __restrict__ x,
                const float* __restrict__ W1, const float* __restrict__ b1,
                const float* __restrict__ W2, const float* __restrict__ b2,
                const float* __restrict__ W3, const float* __restrict__ b3,
                const float* __restrict__ G, float* __restrict__ out) {
  const int tid = threadIdx.x;
  const int b   = blockIdx.x;

  __shared__ __align__(16) float h1_l[H_];
  __shared__ __align__(16) float d1_l[H_];
  __shared__ __align__(16) float h2_l[H_];
  __shared__ __align__(16) float d2_l[H_];
  __shared__ __align__(16) float gv_l[H_];
  __shared__ float inp[D_+1];
  __shared__ float out_l[D_];
  __shared__ float tr_l;
  __shared__ float z_l[D_+1], z5_l[D_+1];
  __shared__ float ks_l[7][D_+1];
  __shared__ float ctrl_t, ctrl_dt;
  __shared__ int   ctrl_acc, ctrl_done;

  // ---- weights into registers (static indexing only) ----
  // wA: threads [0,256): W2 half-row (row=tid>>1, half=tid&1)
  //     threads [256,512): G half-row (row=(tid-256)>>1, half=tid&1)
  // wB: threads [0,128): W1 row (33); threads [256,384): W3 chunk (32)
  float wA[64];
  float wB[33];
  float rb1 = 0.f, rb2 = 0.f, rb3 = 0.f;
  {
    const int half = tid & 1;
    if (tid < 256) {
      const int r = tid >> 1;
      const float* p = W2 + r*H_ + half*64;
      #pragma unroll
      for (int j = 0; j < 64; ++j) wA[j] = p[j];
      rb2 = b2[r];
    } else {
      const int r = (tid - 256) >> 1;
      const float* p = G + r*H_ + half*64;
      #pragma unroll
      for (int j = 0; j < 64; ++j) wA[j] = p[j];
    }
    if (tid < 128) {
      const float* p = W1 + tid*(D_+1);
      #pragma unroll
      for (int j = 0; j < 33; ++j) wB[j] = p[j];
      rb1 = b1[tid];
    } else if (tid >= 256 && tid < 384) {
      const int r = (tid - 256) >> 2, c = tid & 3;
      const float* p = W3 + r*H_ + c*32;
      #pragma unroll
      for (int j = 0; j < 32; ++j) wB[j] = p[j];
      wB[32] = 0.f;
      rb3 = b3[r];
    } else {
      #pragma unroll
      for (int j = 0; j < 33; ++j) wB[j] = 0.f;
    }
  }

  // f_aug evaluation: reads inp[0..32] (x-part + t_eff), leaves out_l (dxdt) and tr_l (trace)
  auto f_eval = [&]() {
    // Phase A: layer 1 (threads 0..127, one row each)
    if (tid < H_) {
      float a0 = rb1, a1 = 0.f, a2 = 0.f, a3 = 0.f;
      #pragma unroll
      for (int d = 0; d < 32; d += 4) {
        a0 += wB[d]   * inp[d];
        a1 += wB[d+1] * inp[d+1];
        a2 += wB[d+2] * inp[d+2];
        a3 += wB[d+3] * inp[d+3];
      }
      float u = ((a0+a1)+(a2+a3)) + wB[32]*inp[32];
      float h = tanhf(u);
      h1_l[tid] = h;
      d1_l[tid] = 1.f - h*h;
    }
    __syncthreads();
    // Phase B: u2 = W2 h1 (waves 0-3)  ||  gv = G d1 (waves 4-7), half-row per thread
    {
      const float* vec = (tid < 256) ? h1_l : d1_l;
      const float4* v4 = reinterpret_cast<const float4*>(vec + (tid & 1)*64);
      float a0 = 0.f, a1 = 0.f, a2 = 0.f, a3 = 0.f;
      #pragma unroll
      for (int c = 0; c < 16; ++c) {
        float4 v = v4[c];
        a0 += wA[4*c]   * v.x;
        a1 += wA[4*c+1] * v.y;
        a2 += wA[4*c+2] * v.z;
        a3 += wA[4*c+3] * v.w;
      }
      float acc = (a0+a1)+(a2+a3);
      acc += __shfl_xor(acc, 1);
      if ((tid & 1) == 0) {
        const int row = (tid >> 1) & (H_-1);
        if (tid < 256) {
          float h = tanhf(acc + rb2);
          h2_l[row] = h;
          d2_l[row] = 1.f - h*h;
        } else {
          gv_l[row] = acc;
        }
      }
    }
    __syncthreads();
    // Phase C: out = W3 h2 + b3 (threads 256..383, quarter-row each)  ||  trace reduce (wave 0)
    if (tid >= 256 && tid < 384) {
      const int c = tid & 3;
      const float4* h4 = reinterpret_cast<const float4*>(h2_l + c*32);
      float a0 = 0.f, a1 = 0.f, a2 = 0.f, a3 = 0.f;
      #pragma unroll
      for (int cc = 0; cc < 8; ++cc) {
        float4 v = h4[cc];
        a0 += wB[4*cc]   * v.x;
        a1 += wB[4*cc+1] * v.y;
        a2 += wB[4*cc+2] * v.z;
        a3 += wB[4*cc+3] * v.w;
      }
      float acc = (a0+a1)+(a2+a3);
      acc += __shfl_xor(acc, 1);
      acc += __shfl_xor(acc, 2);
      if (c == 0) out_l[(tid-256) >> 2] = acc + rb3;
    }
    if (tid < 64) {
      float p = d2_l[tid]*gv_l[tid] + d2_l[tid+64]*gv_l[tid+64];
      #pragma unroll
      for (int m = 1; m < 64; m <<= 1) p += __shfl_xor(p, m);
      if (tid == 0) tr_l = p;
    }
    __syncthreads();
  };

  // ---- init ----
  if (tid < 32) { z_l[tid] = x[b*D_ + tid]; inp[tid] = x[b*D_ + tid]; }
  if (tid == 32) { z_l[32] = 0.f; inp[32] = 1.0f; }
  if (tid == 0) { ctrl_t = 0.f; ctrl_dt = 1e-4f; ctrl_acc = 0; ctrl_done = 0; }
  __syncthreads();

  // ks[0] = f(0, z0)   (FSAL slot, maintained across steps)
  f_eval();
  if (tid < 32)       ks_l[0][tid] = -out_l[tid];
  else if (tid == 32) ks_l[0][32]  = -tr_l;

  for (int it = 0; it < NSTEPS; ++it) {
    const float t  = ctrl_t;
    const float dt = ctrl_dt;
    const float dtc = fminf(dt, 1.0f - t);

    // stages 1..6
    for (int s = 1; s <= 6; ++s) {
      if (tid < 32) {
        float zi = z_l[tid];
        for (int j = 0; j < s; ++j) zi += dtc * cA[s-1][j] * ks_l[j][tid];
        inp[tid] = zi;
      } else if (tid == 32) {
        inp[32] = 1.0f - (t + cC[s-1]*dtc);
      }
      __syncthreads();
      f_eval();
      if (tid < 32)       ks_l[s][tid] = -out_l[tid];
      else if (tid == 32) ks_l[s][32]  = -tr_l;
    }

    // z5, error, acceptance
    float qv = 0.f;
    if (tid < 33) {
      const float zc = z_l[tid];
      const float k0 = ks_l[0][tid], k2 = ks_l[2][tid], k3 = ks_l[3][tid];
      const float k4 = ks_l[4][tid], k5 = ks_l[5][tid], k6 = ks_l[6][tid];
      const float z5 = zc + dtc*(cB5[0]*k0 + cB5[2]*k2 + cB5[3]*k3 + cB5[4]*k4 + cB5[5]*k5);
      const float er = dtc*(cE[0]*k0 + cE[2]*k2 + cE[3]*k3 + cE[4]*k4 + cE[5]*k5 + cE[6]*k6);
      z5_l[tid] = z5;
      const float sc = 1e-5f + 1e-3f*fmaxf(fabsf(zc), fabsf(z5));
      const float q = er / sc;
      qv = q*q;
    }
    if (tid < 64) {
      float v = qv;
      #pragma unroll
      for (int m = 1; m < 64; m <<= 1) v += __shfl_xor(v, m);
      if (tid == 0) {
        const float ratio = sqrtf(v * (1.0f/33.0f));
        const int acc = (ratio <= 1.0f) ? 1 : 0;
        float factor = 0.9f * powf(fmaxf(ratio, 1e-10f), -0.2f);
        factor = fminf(fmaxf(factor, 0.2f), 10.0f);
        const float tn = acc ? (t + dtc) : t;
        ctrl_t = tn;
        ctrl_dt = dtc * factor;
        ctrl_acc = acc;
        ctrl_done = (tn >= (float)(1.0 - 1e-10)) ? 1 : 0;
      }
    }
    __syncthreads();
    if (ctrl_acc) {
      if (tid < 33) {
        z_l[tid] = z5_l[tid];
        ks_l[0][tid] = ks_l[6][tid];   // FSAL: f(t_n, z_n) == stage-6 eval, bit-compatible
      }
    }
    const int done = ctrl_done;
    __syncthreads();
    if (done) break;
  }

  if (tid < 32) out[b*D_ + tid] = z_l[tid];
  if (tid == 0) out[B_*D_ + b]  = z_l[32];
}

extern "C" void kernel_launch(void* const* d_in, const int* in_sizes, int n_in,
                              void* d_out, int out_size, void* d_ws, size_t ws_size,
                              hipStream_t stream) {
  const float* x  = (const float*)d_in[0];
  const float* W1 = (const float*)d_in[1];
  const float* b1 = (const float*)d_in[2];
  const float* W2 = (const float*)d_in[3];
  const float* b2 = (const float*)d_in[4];
  const float* W3 = (const float*)d_in[5];
  const float* b3 = (const float*)d_in[6];
  float* out = (float*)d_out;
  float* G   = (float*)d_ws;   // 128*128*4 = 64 KiB scratch

  hipLaunchKernelGGL(g_precompute, dim3(H_), dim3(H_), 0, stream, W1, W2, W3, G);
  hipLaunchKernelGGL(node_solve, dim3(B_), dim3(512), 0, stream,
                     x, W1, b1, W2, b2, W3, b3, G, out);
}

// Round 2
// 53.073 us; speedup vs baseline: 1.2895x; 1.2895x over previous
//
#include <hip/hip_runtime.h>

#define D_ 32
#define H_ 128
#define B_ 32
#define NSTEPS 48

template<int N> struct IC { static constexpr int v = N; };

// Dormand-Prince coefficients (double-computed, f32-rounded like JAX weak typing)
constexpr float fA[6][6] = {
  {(float)(0.2), 0.f, 0.f, 0.f, 0.f, 0.f},
  {(float)(3.0/40.0), (float)(9.0/40.0), 0.f, 0.f, 0.f, 0.f},
  {(float)(44.0/45.0), (float)(-56.0/15.0), (float)(32.0/9.0), 0.f, 0.f, 0.f},
  {(float)(19372.0/6561.0), (float)(-25360.0/2187.0), (float)(64448.0/6561.0), (float)(-212.0/729.0), 0.f, 0.f},
  {(float)(9017.0/3168.0), (float)(-355.0/33.0), (float)(46732.0/5247.0), (float)(49.0/176.0), (float)(-5103.0/18656.0), 0.f},
  {(float)(35.0/384.0), 0.f, (float)(500.0/1113.0), (float)(125.0/192.0), (float)(-2187.0/6784.0), (float)(11.0/84.0)}
};
constexpr float fC[6] = {0.2f, 0.3f, 0.8f, (float)(8.0/9.0), 1.0f, 1.0f};
constexpr float fB5[6] = {(float)(35.0/384.0), 0.f, (float)(500.0/1113.0), (float)(125.0/192.0),
                          (float)(-2187.0/6784.0), (float)(11.0/84.0)};
constexpr float fE[7] = {
  (float)(35.0/384.0 - 5179.0/57600.0), 0.f,
  (float)(500.0/1113.0 - 7571.0/16695.0),
  (float)(125.0/192.0 - 393.0/640.0),
  (float)(-2187.0/6784.0 + 92097.0/339200.0),
  (float)(11.0/84.0 - 187.0/2100.0),
  (float)(-1.0/40.0)
};

// G[k][i] = W2[k][i] * M[i][k],  M[i][k] = sum_d W1[i][d] * W3[d][k]  (d < D)
// trace(J) = d2^T (G d1)   [input-independent, precomputed once]
__global__ void g_precompute(const float* __restrict__ W1, const float* __restrict__ W2,
                             const float* __restrict__ W3, float* __restrict__ G) {
  int k = blockIdx.x;
  int i = threadIdx.x;
  float m = 0.f;
  #pragma unroll
  for (int d = 0; d < D_; ++d) m += W1[i*(D_+1) + d] * W3[d*H_ + k];
  G[k*H_ + i] = W2[k*H_ + i] * m;
}

__global__ __launch_bounds__(512)
void node_solve(const float* __restrict__ x,
                const float* __restrict__ W1, const float* __restrict__ b1,
                const float* __restrict__ W2, const float* __restrict__ b2,
                const float* __restrict__ W3, const float* __restrict__ b3,
                const float* __restrict__ G, float* __restrict__ out) {
  const int tid = threadIdx.x;
  const int b   = blockIdx.x;

  __shared__ __align__(16) float h1_l[H_];
  __shared__ __align__(16) float d1_l[H_];
  __shared__ __align__(16) float h2_l[H_];
  __shared__ __align__(16) float d2_l[H_];
  __shared__ __align__(16) float gv_l[H_];
  __shared__ __align__(16) float inp[36];   // [0..31]=x, [32]=t_eff
  __shared__ float z_l[D_];
  __shared__ float ks_l[7][D_];             // x-components of k only
  __shared__ float ctrl_t, ctrl_dtc;
  __shared__ int   ctrl_done;

  // ---- weights into registers (all static indexing; permuted for bank-friendly reads) ----
  // wA: phase B 4x16 tile. tid<256: W2 rows 4rg..4rg+3, cols 16cg..; tid>=256: G same.
  //     column chunks permuted by cg so LDS reads rotate banks.
  // wB: tid<128: W1 row (33); tid in [256,384): W3 quarter-row, chunks rotated by 2c.
  float wA[64];
  float wB[33];
  float rb1 = 0.f, rb3 = 0.f;
  float4 rb2q = make_float4(0.f, 0.f, 0.f, 0.f);

  const int lt = tid & 255;
  const int rg = lt >> 3;   // 0..31 -> rows 4rg..4rg+3
  const int cg = lt & 7;    // 0..7  -> cols 16cg..16cg+15
  {
    const float* Wsrc = (tid < 256) ? W2 : G;
    #pragma unroll
    for (int j = 0; j < 4; ++j) {
      const float* p = Wsrc + (4*rg + j)*H_ + cg*16;
      #pragma unroll
      for (int k = 0; k < 4; ++k) {
        const int src = 4*((k + cg) & 3);
        #pragma unroll
        for (int e = 0; e < 4; ++e) wA[16*j + 4*k + e] = p[src + e];
      }
    }
    if (tid < 256) rb2q = *reinterpret_cast<const float4*>(b2 + 4*rg);
  }
  if (tid < 128) {
    const float* p = W1 + tid*(D_+1);
    #pragma unroll
    for (int j = 0; j < 33; ++j) wB[j] = p[j];
    rb1 = b1[tid];
  } else if (tid >= 256 && tid < 384) {
    const int r = (tid - 256) >> 2, c = tid & 3;
    const float* p = W3 + r*H_ + c*32;
    #pragma unroll
    for (int jj = 0; jj < 8; ++jj) {
      const int src = 4*((jj + 2*c) & 7);
      #pragma unroll
      for (int e = 0; e < 4; ++e) wB[4*jj + e] = p[src + e];
    }
    wB[32] = 0.f;
    rb3 = b3[r];
  }

  // branchless fast tanh: 1 - 2/(e^{2u}+1); exact at +-inf saturation
  auto tanh_f = [](float u) {
    float e = exp2f(2.885390081777927f * u);
    return 1.0f - 2.0f * __builtin_amdgcn_rcpf(e + 1.0f);
  };

  // Phase A: layer 1 (threads 0..127), inp broadcast-read as float4
  auto phaseA = [&]() {
    if (tid < H_) {
      const float4* iv = reinterpret_cast<const float4*>(inp);
      float a0 = rb1, a1 = 0.f, a2 = 0.f, a3 = 0.f;
      #pragma unroll
      for (int k = 0; k < 8; ++k) {
        float4 v = iv[k];
        a0 += wB[4*k]   * v.x;
        a1 += wB[4*k+1] * v.y;
        a2 += wB[4*k+2] * v.z;
        a3 += wB[4*k+3] * v.w;
      }
      float u = ((a0+a1)+(a2+a3)) + wB[32]*inp[32];
      float h = tanh_f(u);
      h1_l[tid] = h;
      d1_l[tid] = 1.f - h*h;
    }
  };

  // Phase B: u2 = W2 h1 (tid<256) || gv = G d1 (tid>=256); 4x16 tile per thread
  auto phaseB = [&]() {
    const float* vec  = (tid < 256) ? h1_l : d1_l;
    const float* base = vec + cg*16;
    float4 va[4];
    #pragma unroll
    for (int k = 0; k < 4; ++k)
      va[k] = *reinterpret_cast<const float4*>(base + 4*((k + cg) & 3));
    float accv[4];
    #pragma unroll
    for (int j = 0; j < 4; ++j) {
      float s0=0.f, s1=0.f, s2=0.f, s3=0.f;
      #pragma unroll
      for (int k = 0; k < 4; ++k) {
        s0 += wA[16*j+4*k+0]*va[k].x;
        s1 += wA[16*j+4*k+1]*va[k].y;
        s2 += wA[16*j+4*k+2]*va[k].z;
        s3 += wA[16*j+4*k+3]*va[k].w;
      }
      accv[j] = (s0+s1)+(s2+s3);
    }
    #pragma unroll
    for (int j = 0; j < 4; ++j) {
      accv[j] += __shfl_xor(accv[j], 1);
      accv[j] += __shfl_xor(accv[j], 2);
      accv[j] += __shfl_xor(accv[j], 4);
    }
    if (cg == 0) {
      if (tid < 256) {
        float t0 = tanh_f(accv[0] + rb2q.x);
        float t1 = tanh_f(accv[1] + rb2q.y);
        float t2 = tanh_f(accv[2] + rb2q.z);
        float t3 = tanh_f(accv[3] + rb2q.w);
        *reinterpret_cast<float4*>(h2_l + 4*rg) = make_float4(t0, t1, t2, t3);
        *reinterpret_cast<float4*>(d2_l + 4*rg) =
            make_float4(1.f-t0*t0, 1.f-t1*t1, 1.f-t2*t2, 1.f-t3*t3);
      } else {
        *reinterpret_cast<float4*>(gv_l + 4*rg) = make_float4(accv[0], accv[1], accv[2], accv[3]);
      }
    }
  };

  // Phase C (stage S): W3 matvec (tid 256..383, rotated conflict-free reads), writes ks_l[S],
  // folds next-stage input prep (S<6), wave0 computes trace lane-partial (returned).
  auto phaseC = [&](auto Sc, float dtc, float t) -> float {
    constexpr int S = decltype(Sc)::v;
    if (tid >= 256 && tid < 384) {
      const int r = (tid - 256) >> 2, c = tid & 3;
      const float* base = h2_l + c*32;
      float s0=0.f, s1=0.f, s2=0.f, s3=0.f;
      #pragma unroll
      for (int jj = 0; jj < 8; ++jj) {
        float4 v = *reinterpret_cast<const float4*>(base + 4*((jj + 2*c) & 7));
        s0 += wB[4*jj+0]*v.x;
        s1 += wB[4*jj+1]*v.y;
        s2 += wB[4*jj+2]*v.z;
        s3 += wB[4*jj+3]*v.w;
      }
      float acc = (s0+s1)+(s2+s3);
      acc += __shfl_xor(acc, 1);
      acc += __shfl_xor(acc, 2);
      if (c == 0) {
        float k = -(acc + rb3);
        ks_l[S][r] = k;
        if constexpr (S < 6) {
          float zi = z_l[r];
          #pragma unroll
          for (int j = 0; j < S; ++j) zi += dtc * fA[S][j] * ks_l[j][r];
          zi += dtc * fA[S][S] * k;
          inp[r] = zi;
        }
      }
    }
    if constexpr (S < 6) {
      if (tid == 384) inp[32] = 1.0f - (t + fC[S]*dtc);
    }
    float p = 0.f;
    if (tid < 64) p = d2_l[tid]*gv_l[tid] + d2_l[tid+64]*gv_l[tid+64];
    return p;
  };

  // ---- init ----
  if (tid < 32) { float xv = x[b*D_ + tid]; z_l[tid] = xv; inp[tid] = xv; }
  if (tid == 32) inp[32] = 1.0f;   // t_eff at t=0
  if (tid == 0) { ctrl_t = 0.f; ctrl_dtc = 1e-4f; ctrl_done = 0; }
  float z32 = 0.f;
  float pk0=0.f, pk1=0.f, pk2=0.f, pk3=0.f, pk4=0.f, pk5=0.f, pk6=0.f;
  __syncthreads();

  // initial eval: ks[0] = f(0, z0); also preps stage-1 input
  phaseA(); __syncthreads();
  phaseB(); __syncthreads();
  pk0 = phaseC(IC<0>{}, 1e-4f, 0.f); __syncthreads();

  for (int it = 0; it < NSTEPS; ++it) {
    const float t   = ctrl_t;
    const float dtc = ctrl_dtc;

    phaseA(); __syncthreads(); phaseB(); __syncthreads();
    pk1 = phaseC(IC<1>{}, dtc, t); __syncthreads();
    phaseA(); __syncthreads(); phaseB(); __syncthreads();
    pk2 = phaseC(IC<2>{}, dtc, t); __syncthreads();
    phaseA(); __syncthreads(); phaseB(); __syncthreads();
    pk3 = phaseC(IC<3>{}, dtc, t); __syncthreads();
    phaseA(); __syncthreads(); phaseB(); __syncthreads();
    pk4 = phaseC(IC<4>{}, dtc, t); __syncthreads();
    phaseA(); __syncthreads(); phaseB(); __syncthreads();
    pk5 = phaseC(IC<5>{}, dtc, t); __syncthreads();
    phaseA(); __syncthreads(); phaseB(); __syncthreads();
    pk6 = phaseC(IC<6>{}, dtc, t); __syncthreads();

    // ---- error / accept / update / next-step prep: all inside wave 0, no extra barriers ----
    if (tid < 64) {
      float qv = 0.f, z5r = 0.f, zcr = 0.f, k0r = 0.f, k6r = 0.f;
      if (tid < 32) {
        zcr = z_l[tid];
        float k0 = ks_l[0][tid], k2 = ks_l[2][tid], k3 = ks_l[3][tid],
              k4 = ks_l[4][tid], k5 = ks_l[5][tid], k6 = ks_l[6][tid];
        k0r = k0; k6r = k6;
        z5r = zcr + dtc*(fB5[0]*k0 + fB5[2]*k2 + fB5[3]*k3 + fB5[4]*k4 + fB5[5]*k5);
        float er = dtc*(fE[0]*k0 + fE[2]*k2 + fE[3]*k3 + fE[4]*k4 + fE[5]*k5 + fE[6]*k6);
        float sc = 1e-5f + 1e-3f*fmaxf(fabsf(zcr), fabsf(z5r));
        float q = er / sc;
        qv = q*q;
      }
      // deferred trace: linear-combine lane partials, reduce once (3 values, one butterfly)
      float zp = fB5[0]*pk0 + fB5[2]*pk2 + fB5[3]*pk3 + fB5[4]*pk4 + fB5[5]*pk5;
      float ep = fE[0]*pk0 + fE[2]*pk2 + fE[3]*pk3 + fE[4]*pk4 + fE[5]*pk5 + fE[6]*pk6;
      #pragma unroll
      for (int m = 1; m < 64; m <<= 1) {
        qv += __shfl_xor(qv, m);
        zp += __shfl_xor(zp, m);
        ep += __shfl_xor(ep, m);
      }
      const float z5_32 = z32 - dtc*zp;     // k[32] = -trace
      const float er32  = -dtc*ep;
      const float sc32  = 1e-5f + 1e-3f*fmaxf(fabsf(z32), fabsf(z5_32));
      const float q32   = er32 / sc32;
      const float ratio = sqrtf((qv + q32*q32) * (1.0f/33.0f));
      const bool  acc   = (ratio <= 1.0f);
      float fac = 0.9f * exp2f(-0.2f * log2f(fmaxf(ratio, 1e-10f)));
      fac = fminf(fmaxf(fac, 0.2f), 10.0f);
      const float tn   = acc ? (t + dtc) : t;
      const float dtn  = dtc * fac;
      const float dtc2 = fminf(dtn, 1.0f - tn);
      const int   dn   = (tn >= 1.0f) ? 1 : 0;
      if (acc) { z32 = z5_32; pk0 = pk6; }
      if (tid < 32) {
        const float zn  = acc ? z5r : zcr;
        const float k0n = acc ? k6r : k0r;
        z_l[tid] = zn;
        if (acc) ks_l[0][tid] = k6r;          // FSAL
        inp[tid] = zn + dtc2 * 0.2f * k0n;    // stage-1 prep for next step
      }
      if (tid == 32) inp[32] = 1.0f - (tn + 0.2f*dtc2);
      if (tid == 0) { ctrl_t = tn; ctrl_dtc = dtc2; ctrl_done = dn; }
    }
    __syncthreads();
    if (ctrl_done) break;
  }

  if (tid < 32) out[b*D_ + tid] = z_l[tid];
  if (tid == 0) out[B_*D_ + b]  = z32;
}

extern "C" void kernel_launch(void* const* d_in, const int* in_sizes, int n_in,
                              void* d_out, int out_size, void* d_ws, size_t ws_size,
                              hipStream_t stream) {
  const float* x  = (const float*)d_in[0];
  const float* W1 = (const float*)d_in[1];
  const float* b1 = (const float*)d_in[2];
  const float* W2 = (const float*)d_in[3];
  const float* b2 = (const float*)d_in[4];
  const float* W3 = (const float*)d_in[5];
  const float* b3 = (const float*)d_in[6];
  float* out = (float*)d_out;
  float* G   = (float*)d_ws;   // 128*128*4 = 64 KiB scratch

  hipLaunchKernelGGL(g_precompute, dim3(H_), dim3(H_), 0, stream, W1, W2, W3, G);
  hipLaunchKernelGGL(node_solve, dim3(B_), dim3(512), 0, stream,
                     x, W1, b1, W2, b2, W3, b3, G, out);
}